// Round 9
// baseline (151.526 us; speedup 1.0000x reference)
//
#include <hip/hip_runtime.h>
#include <hip/hip_bf16.h>
#include <stdint.h>
#include <math.h>

#define NHEAD 16
#define DK 64
#define SEQ 2048
#define BATCH 2
#define DMODEL 1024

typedef __attribute__((ext_vector_type(8))) short short8_t;
typedef __attribute__((ext_vector_type(4))) short short4_t;
typedef __attribute__((ext_vector_type(4))) float f32x4;

#define MFMA(a, b, c) __builtin_amdgcn_mfma_f32_16x16x32_bf16(a, b, c, 0, 0, 0)
#define MFMA16(a, b, c) __builtin_amdgcn_mfma_f32_16x16x16bf16_1k(a, b, c, 0, 0, 0)

__device__ __forceinline__ unsigned short f2bf(float f) {
    union { __hip_bfloat16 b; unsigned short u; } c;
    c.b = __float2bfloat16(f);
    return c.u;
}

// ---------------------------------------------------------------------------
// bucket_kernel: per (bh, which) stable-partition indices by hash value.
// order[pos] = original idx; inv[idx] = pos; cnts[which*32+bh] = #zeros.
// ---------------------------------------------------------------------------
__global__ __launch_bounds__(256) void bucket_kernel(
    const int* __restrict__ hq, const int* __restrict__ hk,
    int* __restrict__ qorder, int* __restrict__ korder,
    int* __restrict__ qinv, int* __restrict__ kinv, int* __restrict__ cnts)
{
    const int blk = blockIdx.x;          // 0..63
    const int bh = blk >> 1;
    const int which = blk & 1;
    const int* src = (which ? hk : hq) + (size_t)bh * SEQ;
    int* dst = (which ? korder : qorder) + (size_t)bh * SEQ;
    int* ivd = (which ? kinv : qinv) + (size_t)bh * SEQ;

    __shared__ int cnt[257];
    const int t = threadIdx.x;           // 0..255
    int h[8]; int c = 0;
#pragma unroll
    for (int j = 0; j < 8; j++) { h[j] = src[t * 8 + j]; c += (h[j] == 0); }
    cnt[t] = c;
    __syncthreads();
    if (t == 0) {
        int run = 0;
        for (int i = 0; i < 256; i++) { int v = cnt[i]; cnt[i] = run; run += v; }
        cnt[256] = run;
    }
    __syncthreads();
    const int nz = cnt[256];
    int zpos = cnt[t];
    int opos = nz + t * 8 - cnt[t];
#pragma unroll
    for (int j = 0; j < 8; j++) {
        int idx = t * 8 + j;
        if (h[j] == 0) { dst[zpos] = idx; ivd[idx] = zpos; zpos++; }
        else           { dst[opos] = idx; ivd[idx] = opos; opos++; }
    }
    if (t == 0) cnts[which * 32 + bh] = nz;
}

// ---------------------------------------------------------------------------
// cvt_xw: X (4M f32) -> bf16, W (1M f32) -> bf16.
// ---------------------------------------------------------------------------
__global__ __launch_bounds__(256) void cvt_xw_kernel(
    const float* __restrict__ X, const float* __restrict__ W,
    unsigned short* __restrict__ Xb, unsigned short* __restrict__ Wb)
{
    const size_t t = (size_t)blockIdx.x * 256 + threadIdx.x;
    const float* src;
    unsigned short* dst;
    size_t i8;
    if (t < 524288) { src = X; dst = Xb; i8 = t * 8; }
    else            { src = W; dst = Wb; i8 = (t - 524288) * 8; }
    f32x4 v0 = *(const f32x4*)(src + i8);
    f32x4 v1 = *(const f32x4*)(src + i8 + 4);
    union { short8_t v; unsigned short u[8]; } o;
#pragma unroll
    for (int j = 0; j < 4; j++) {
        o.u[j]     = f2bf(v0[j]);
        o.u[4 + j] = f2bf(v1[j]);
    }
    *(short8_t*)(dst + i8) = o.v;
}

// ---------------------------------------------------------------------------
// proj_nat: natural-order GEMM, tile 128x128, BK=64, dbuf global_load_lds.
// MODE 0: C[gm][od] = X@W^T + b; scatter rows via inv -> dst[bh][pos][d] (Q/K)
// MODE 1: C[od][gm] = W@X^T + b; natural store    -> dst[bh][d][gm]     (V)
// Grid 256 flat, XCD-chunked on the X dimension (1MB X chunk + 2MB W per L2).
// ---------------------------------------------------------------------------
template <int MODE>
__global__ __launch_bounds__(256) void proj_nat(
    const unsigned short* __restrict__ Xb,   // [4096][1024]
    const unsigned short* __restrict__ Wb,   // [1024][1024]
    const float* __restrict__ bias,
    const int* __restrict__ inv,             // [32][2048] (MODE 0)
    unsigned short* __restrict__ dst)
{
    __shared__ unsigned short At[2][128 * 64];
    __shared__ unsigned short Bt[2][128 * 64];

    const int tid = threadIdx.x;
    const int lane = tid & 63;
    const int wv = tid >> 6;
    const int fr = lane & 15;
    const int fg = lane >> 4;
    const int srw = lane >> 3;
    const int su = lane & 7;

    const int flat = blockIdx.x;            // 0..255
    const int xcd = flat >> 5;
    const int idx = flat & 31;
    const int xtile = xcd * 4 + (idx & 3);  // 0..31  (X-row tiles)
    const int wtile = idx >> 2;             // 0..7   (W-row tiles)

    const unsigned short* Ap; const unsigned short* Bp;
    int m0, n0;
    if constexpr (MODE == 0) { Ap = Xb; Bp = Wb; m0 = xtile * 128; n0 = wtile * 128; }
    else                     { Ap = Wb; Bp = Xb; m0 = wtile * 128; n0 = xtile * 128; }

    // hoisted per-lane staging sources (wave wv stages rows [wv*32, +32))
    const unsigned short* aS[4]; const unsigned short* bS[4];
#pragma unroll
    for (int i = 0; i < 4; i++) {
        int r = wv * 32 + i * 8 + srw;
        aS[i] = Ap + (size_t)(m0 + r) * DMODEL + ((su ^ (r & 7)) << 3);
        bS[i] = Bp + (size_t)(n0 + r) * DMODEL + ((su ^ (r & 7)) << 3);
    }

    f32x4 acc[2][8];
    const f32x4 fzero = {0.f, 0.f, 0.f, 0.f};
#pragma unroll
    for (int mf = 0; mf < 2; mf++)
#pragma unroll
        for (int nf = 0; nf < 8; nf++) acc[mf][nf] = fzero;

#define PSTAGE(K0, BI)                                                        \
    {                                                                         \
        _Pragma("unroll")                                                     \
        for (int i = 0; i < 4; i++) {                                         \
            __builtin_amdgcn_global_load_lds(                                 \
                (const void*)(aS[i] + (K0)),                                  \
                (void*)&At[BI][(wv * 32 + i * 8) * 64], 16, 0, 0);            \
            __builtin_amdgcn_global_load_lds(                                 \
                (const void*)(bS[i] + (K0)),                                  \
                (void*)&Bt[BI][(wv * 32 + i * 8) * 64], 16, 0, 0);            \
        }                                                                     \
    }

    PSTAGE(0, 0);
    __syncthreads();
    int cur = 0;

    for (int kk = 0; kk < 16; kk++) {
        if (kk < 15) PSTAGE((kk + 1) * 64, cur ^ 1);

        short8_t a[2][2];
#pragma unroll
        for (int mf = 0; mf < 2; mf++)
#pragma unroll
            for (int ks = 0; ks < 2; ks++) {
                int r = wv * 32 + mf * 16 + fr;
                int u = (ks * 4 + fg) ^ (fr & 7);
                a[mf][ks] = *(const short8_t*)&At[cur][r * 64 + u * 8];
            }
#pragma unroll
        for (int nf = 0; nf < 8; nf++) {
            int rB = nf * 16 + fr;
            short8_t b0 = *(const short8_t*)&Bt[cur][rB * 64 + ((fg ^ (fr & 7)) << 3)];
            short8_t b1 = *(const short8_t*)&Bt[cur][rB * 64 + (((4 + fg) ^ (fr & 7)) << 3)];
            acc[0][nf] = MFMA(a[0][0], b0, acc[0][nf]);
            acc[0][nf] = MFMA(a[0][1], b1, acc[0][nf]);
            acc[1][nf] = MFMA(a[1][0], b0, acc[1][nf]);
            acc[1][nf] = MFMA(a[1][1], b1, acc[1][nf]);
        }
        __syncthreads();
        cur ^= 1;
    }
#undef PSTAGE

#pragma unroll
    for (int mf = 0; mf < 2; mf++)
#pragma unroll
        for (int nf = 0; nf < 8; nf++)
#pragma unroll
            for (int r = 0; r < 4; r++) {
                if constexpr (MODE == 0) {
                    int gm = m0 + wv * 32 + mf * 16 + fg * 4 + r;   // b*2048+l
                    int dd = n0 + nf * 16 + fr;                     // h*64+d
                    float v = acc[mf][nf][r] + bias[dd];
                    int bb = gm >> 11, h = dd >> 6;
                    int bh = bb * NHEAD + h;
                    int pos = inv[(size_t)bh * SEQ + (gm & (SEQ - 1))];
                    dst[((size_t)bh * SEQ + pos) * DK + (dd & 63)] = f2bf(v);
                } else {
                    int od = m0 + wv * 32 + mf * 16 + fg * 4 + r;   // h*64+d
                    int gm = n0 + nf * 16 + fr;                     // b*2048+l
                    float v = acc[mf][nf][r] + bias[od];
                    int bb = gm >> 11, h = od >> 6;
                    int bh = bb * NHEAD + h;
                    dst[((size_t)bh * DK + (od & 63)) * SEQ + (gm & (SEQ - 1))] = f2bf(v);
                }
            }
}

// ---------------------------------------------------------------------------
// vperm: Vs[bh][d][pos] = Vn[bh][d][korder[bh][pos]]  (gather along keys)
// ---------------------------------------------------------------------------
__global__ __launch_bounds__(256) void vperm_kernel(
    const unsigned short* __restrict__ Vn, const int* __restrict__ korder,
    unsigned short* __restrict__ Vs)
{
    const int blk = blockIdx.x;       // 0..2047 = bh*64 + d
    const int bh = blk >> 6;
    const int d  = blk & 63;
    const int t = threadIdx.x;        // pos = t*8
    const int* kop = korder + (size_t)bh * SEQ + t * 8;
    const unsigned short* src = Vn + ((size_t)bh * DK + d) * SEQ;
    union { short8_t v; unsigned short u[8]; } o;
#pragma unroll
    for (int j = 0; j < 8; j++) o.u[j] = src[kop[j]];
    *(short8_t*)(Vs + ((size_t)bh * DK + d) * SEQ + t * 8) = o.v;
}

// ---------------------------------------------------------------------------
// LSH flash attention: bucket-sorted, bucket-aligned q-slots, swapped QK^T,
// in-register PV (16x16x16), V-frags hoisted before softmax, psum via MFMA.
// ---------------------------------------------------------------------------
__global__ __launch_bounds__(256) void lsh_attn_kernel(
    const unsigned short* __restrict__ Qs,
    const unsigned short* __restrict__ Ks, const unsigned short* __restrict__ Vst,
    const int* __restrict__ qorder, const int* __restrict__ cnts,
    float* __restrict__ out)
{
    __shared__ unsigned short KtL[2][64 * 64];
    __shared__ unsigned short VtL[2][64 * 64];

    const int tid = threadIdx.x;
    const int lane = tid & 63;
    const int wv = tid >> 6;
    const int fr = lane & 15;
    const int fg = lane >> 4;

    // XCD-grouped mapping: 1056 = 8 XCD x (4 heads x 33 slots)
    const int flat = blockIdx.x;
    const int xcd = flat & 7;
    const int s2 = flat >> 3;                 // 0..131
    const int bh = (xcd << 2) + (s2 / 33);    // b*16 + h
    const int slot = s2 % 33;

    const int nq0 = cnts[bh];
    const int nk0 = cnts[32 + bh];
    const int c0 = (nq0 + 63) >> 6;           // q-tiles covering bucket 0

    int B, qlo, qhi;
    if (slot < c0) {
        B = 0; qlo = slot << 6; qhi = min(qlo + 64, nq0);
    } else {
        B = 1; qlo = nq0 + ((slot - c0) << 6);
        if (qlo >= SEQ) return;               // uniform: safe before barriers
        qhi = min(qlo + 64, SEQ);
    }
    const int klo = B ? (nk0 >> 6) : 0;
    const int khi = B ? (SEQ >> 6) : ((nk0 + 63) >> 6);
    const int nt = khi - klo;

    const size_t base = (size_t)bh * SEQ * DK;
    const unsigned short* Kb = Ks + base;                    // [pos][d]
    const unsigned short* Vb = Vst + (size_t)bh * DK * SEQ;  // [d][pos]

    const int srw = lane >> 3;
    const int su = lane & 7;

    // Q fragments (B-operand of swapped QK: lane fr = q-row qlo + wv*16 + fr)
    short8_t q_hi[2];
    {
        const size_t ro = base + (size_t)(qlo + wv * 16 + fr) * DK;
        q_hi[0] = *(const short8_t*)(Qs + ro + fg * 8);
        q_hi[1] = *(const short8_t*)(Qs + ro + 32 + fg * 8);
    }

    const int swz = fr & 7;
    const int u0 = ((fg ^ swz) << 3);
    const int u1 = (((4 + fg) ^ swz) << 3);
    int vuoff[4];
#pragma unroll
    for (int kg = 0; kg < 4; kg++)
        vuoff[kg] = (((kg * 2 + (fg >> 1)) ^ swz) << 3) + ((fg & 1) << 2);

    const float C2 = 0.18033688011112042f;    // 0.125 * log2(e)
    const float B2 = -14.426950408889634f;    // -10 * log2(e)

    const short4_t ones = {(short)0x3F80, (short)0x3F80, (short)0x3F80, (short)0x3F80};
    f32x4 acc_sum;
    f32x4 o_acc[4];
    const f32x4 fzero = {0.f, 0.f, 0.f, 0.f};
    acc_sum = fzero;
#pragma unroll
    for (int t = 0; t < 4; t++) o_acc[t] = fzero;

#define STAGE(T, BI)                                                          \
    {                                                                         \
        const int k0s = (T) << 6;                                             \
        _Pragma("unroll")                                                     \
        for (int i = 0; i < 2; i++) {                                         \
            const int r = wv * 16 + i * 8 + srw;                              \
            const int uo = ((su ^ (r & 7)) << 3);                             \
            __builtin_amdgcn_global_load_lds(                                 \
                (const void*)(Kb + (size_t)(k0s + r) * DK + uo),              \
                (void*)&KtL[BI][(wv * 16 + i * 8) * 64], 16, 0, 0);           \
            __builtin_amdgcn_global_load_lds(                                 \
                (const void*)(Vb + (size_t)r * SEQ + k0s + uo),               \
                (void*)&VtL[BI][(wv * 16 + i * 8) * 64], 16, 0, 0);           \
        }                                                                     \
    }

    STAGE(klo, 0);
    __syncthreads();
    int cur = 0;

    for (int i = 0; i < nt; i++) {
        if (i + 1 < nt) STAGE(klo + i + 1, cur ^ 1);   // prefetch next tile

        const int k0 = (klo + i) << 6;

        // ---- V fragments into regs early (independent of S) ----
        short4_t vfr[4][4];
#pragma unroll
        for (int dt = 0; dt < 4; dt++)
#pragma unroll
            for (int kg = 0; kg < 4; kg++)
                vfr[dt][kg] = *(const short4_t*)&VtL[cur][(dt * 16 + fr) * 64 + vuoff[kg]];

        // ---- S^T = K Q^T (8 MFMA; A = K rows, B = Q) ----
        f32x4 s[4];
#pragma unroll
        for (int kg = 0; kg < 4; kg++) {
            const int rr = (kg * 16 + fr) * 64;
            short8_t kc0 = *(const short8_t*)&KtL[cur][rr + u0];
            short8_t kc1 = *(const short8_t*)&KtL[cur][rr + u1];
            f32x4 a = fzero;
            a = MFMA(kc0, q_hi[0], a);
            a = MFMA(kc1, q_hi[1], a);
            s[kg] = a;
        }

        // ---- softmax: p = exp2(s*C2 + B2); boundary tile masks by position ----
        short4_t pk[4];
        const bool mixed = B ? (k0 < nk0) : (k0 + 64 > nk0);
        if (!mixed) {
#pragma unroll
            for (int kg = 0; kg < 4; kg++) {
                union { short4_t v; unsigned short u[4]; } P;
#pragma unroll
                for (int r = 0; r < 4; r++)
                    P.u[r] = f2bf(exp2f(fmaf(s[kg][r], C2, B2)));
                pk[kg] = P.v;
            }
        } else {
#pragma unroll
            for (int kg = 0; kg < 4; kg++) {
                union { short4_t v; unsigned short u[4]; } P;
#pragma unroll
                for (int r = 0; r < 4; r++) {
                    int cb = (k0 + kg * 16 + fg * 4 + r) >= nk0;
                    float basev = (cb == B) ? B2 : -1e9f;
                    P.u[r] = f2bf(exp2f(fmaf(s[kg][r], C2, basev)));
                }
                pk[kg] = P.v;
            }
        }

        // ---- psum via MFMA: acc_sum[.][q] += sum_k P^T[k][q] ----
#pragma unroll
        for (int kg = 0; kg < 4; kg++)
            acc_sum = MFMA16(ones, pk[kg], acc_sum);

        // ---- O^T += V^T P^T (in-register A and B) ----
#pragma unroll
        for (int dt = 0; dt < 4; dt++) {
            f32x4 acc = o_acc[dt];
#pragma unroll
            for (int kg = 0; kg < 4; kg++)
                acc = MFMA16(vfr[dt][kg], pk[kg], acc);
            o_acc[dt] = acc;
        }

        __syncthreads();   // drains prefetch + protects buffer reuse
        cur ^= 1;
    }
#undef STAGE

    // acc_sum rows are identical; element 0 already holds the full psum for q=fr
    const float psum = acc_sum[0];

    // ---- epilogue: row q=fr scatter via qorder; cols contiguous -> float4 ----
    const int b = bh >> 4, h = bh & 15;
    const int qpos = qlo + wv * 16 + fr;
    if (qpos < qhi) {
        const int origq = qorder[(size_t)bh * SEQ + qpos];
        const float inv = 1.0f / psum;
        float* orow = out + ((size_t)(b * SEQ + origq)) * DMODEL + h * DK + fg * 4;
#pragma unroll
        for (int dt = 0; dt < 4; dt++) {
            f32x4 v = o_acc[dt];
            v *= inv;
            *(f32x4*)(orow + dt * 16) = v;
        }
    }
}

// ---------------------------------------------------------------------------

extern "C" void kernel_launch(void* const* d_in, const int* in_sizes, int n_in,
                              void* d_out, int out_size, void* d_ws, size_t ws_size,
                              hipStream_t stream)
{
    const float* query = (const float*)d_in[0];
    const float* key   = (const float*)d_in[1];
    const float* value = (const float*)d_in[2];
    const int* hash_q  = (const int*)d_in[3];
    const int* hash_k  = (const int*)d_in[4];
    const float* Wq    = (const float*)d_in[5];
    const float* bq    = (const float*)d_in[6];
    const float* Wk    = (const float*)d_in[7];
    const float* bk    = (const float*)d_in[8];
    const float* Wv    = (const float*)d_in[9];
    const float* bv    = (const float*)d_in[10];
    float* out = (float*)d_out;

    const size_t plane = (size_t)BATCH * NHEAD * SEQ * DK;   // 4,194,304 elems
    unsigned short* ws = (unsigned short*)d_ws;
    unsigned short* pQ    = ws;
    unsigned short* pK    = ws + plane;
    unsigned short* pVt   = ws + 2 * plane;                   // sorted V^T
    unsigned short* pVn   = ws + 3 * plane;                   // natural V^T
    unsigned short* Xslot = ws + 4 * plane;                   // 4M els
    unsigned short* Wslot = ws + 5 * plane;                   // 1M els
    int* ip = (int*)(ws + 5 * plane + (size_t)DMODEL * DMODEL);
    int* qorder = ip;                 // 32*2048
    int* korder = ip + 65536;
    int* qinv   = ip + 131072;
    int* kinv   = ip + 196608;
    int* cnts   = ip + 262144;        // 64

    bucket_kernel<<<64, 256, 0, stream>>>(hash_q, hash_k, qorder, korder,
                                          qinv, kinv, cnts);

    const int cvtBlocks = (int)((plane + (size_t)DMODEL * DMODEL) / 8 / 256);

    cvt_xw_kernel<<<cvtBlocks, 256, 0, stream>>>(query, Wq, Xslot, Wslot);
    proj_nat<0><<<256, 256, 0, stream>>>(Xslot, Wslot, bq, qinv, pQ);

    cvt_xw_kernel<<<cvtBlocks, 256, 0, stream>>>(key, Wk, Xslot, Wslot);
    proj_nat<0><<<256, 256, 0, stream>>>(Xslot, Wslot, bk, kinv, pK);

    cvt_xw_kernel<<<cvtBlocks, 256, 0, stream>>>(value, Wv, Xslot, Wslot);
    proj_nat<1><<<256, 256, 0, stream>>>(Xslot, Wslot, bv, kinv, pVn);

    vperm_kernel<<<2048, 256, 0, stream>>>(pVn, korder, pVt);

    lsh_attn_kernel<<<dim3(1056), 256, 0, stream>>>(pQ, pK, pVt,
                                                    qorder, cnts, out);
}

// Round 10
// 136.348 us; speedup vs baseline: 1.1113x; 1.1113x over previous
//
#include <hip/hip_runtime.h>
#include <hip/hip_bf16.h>
#include <stdint.h>
#include <math.h>

#define NHEAD 16
#define DK 64
#define SEQ 2048
#define BATCH 2
#define DMODEL 1024

typedef __attribute__((ext_vector_type(8))) short short8_t;
typedef __attribute__((ext_vector_type(4))) short short4_t;
typedef __attribute__((ext_vector_type(4))) float f32x4;

#define MFMA(a, b, c) __builtin_amdgcn_mfma_f32_16x16x32_bf16(a, b, c, 0, 0, 0)
#define MFMA16(a, b, c) __builtin_amdgcn_mfma_f32_16x16x16bf16_1k(a, b, c, 0, 0, 0)

__device__ __forceinline__ unsigned short f2bf(float f) {
    union { __hip_bfloat16 b; unsigned short u; } c;
    c.b = __float2bfloat16(f);
    return c.u;
}

// ---------------------------------------------------------------------------
// bucket_kernel: per (bh, which) stable-partition indices by hash value.
// order[pos] = original idx; inv[idx] = pos; cnts[which*32+bh] = #zeros.
// ---------------------------------------------------------------------------
__global__ __launch_bounds__(256) void bucket_kernel(
    const int* __restrict__ hq, const int* __restrict__ hk,
    int* __restrict__ qorder, int* __restrict__ korder,
    int* __restrict__ qinv, int* __restrict__ kinv, int* __restrict__ cnts)
{
    const int blk = blockIdx.x;          // 0..63
    const int bh = blk >> 1;
    const int which = blk & 1;
    const int* src = (which ? hk : hq) + (size_t)bh * SEQ;
    int* dst = (which ? korder : qorder) + (size_t)bh * SEQ;
    int* ivd = (which ? kinv : qinv) + (size_t)bh * SEQ;

    __shared__ int cnt[257];
    const int t = threadIdx.x;           // 0..255
    int h[8]; int c = 0;
#pragma unroll
    for (int j = 0; j < 8; j++) { h[j] = src[t * 8 + j]; c += (h[j] == 0); }
    cnt[t] = c;
    __syncthreads();
    if (t == 0) {
        int run = 0;
        for (int i = 0; i < 256; i++) { int v = cnt[i]; cnt[i] = run; run += v; }
        cnt[256] = run;
    }
    __syncthreads();
    const int nz = cnt[256];
    int zpos = cnt[t];
    int opos = nz + t * 8 - cnt[t];
#pragma unroll
    for (int j = 0; j < 8; j++) {
        int idx = t * 8 + j;
        if (h[j] == 0) { dst[zpos] = idx; ivd[idx] = zpos; zpos++; }
        else           { dst[opos] = idx; ivd[idx] = opos; opos++; }
    }
    if (t == 0) cnts[which * 32 + bh] = nz;
}

// ---------------------------------------------------------------------------
// cvt_xw: X (4M f32) -> bf16, W (1M f32) -> bf16.
// ---------------------------------------------------------------------------
__global__ __launch_bounds__(256) void cvt_xw_kernel(
    const float* __restrict__ X, const float* __restrict__ W,
    unsigned short* __restrict__ Xb, unsigned short* __restrict__ Wb)
{
    const size_t t = (size_t)blockIdx.x * 256 + threadIdx.x;
    const float* src;
    unsigned short* dst;
    size_t i8;
    if (t < 524288) { src = X; dst = Xb; i8 = t * 8; }
    else            { src = W; dst = Wb; i8 = (t - 524288) * 8; }
    f32x4 v0 = *(const f32x4*)(src + i8);
    f32x4 v1 = *(const f32x4*)(src + i8 + 4);
    union { short8_t v; unsigned short u[8]; } o;
#pragma unroll
    for (int j = 0; j < 4; j++) {
        o.u[j]     = f2bf(v0[j]);
        o.u[4 + j] = f2bf(v1[j]);
    }
    *(short8_t*)(dst + i8) = o.v;
}

// ---------------------------------------------------------------------------
// proj_nat: natural-order GEMM, tile 128(A-rows) x 64(B-rows), BK=64,
// DOUBLE-BUFFERED global_load_lds staging. Grid 512, XCD-grouped on flat&7
// (consecutive blockIdx round-robin across XCDs): each XCD re-reads only its
// 1MB X-chunk + 2MB W from its own L2.
// MODE 0: A=X, B=W. C[gm][od]; scatter rows via inv -> dst[bh][pos][d] (Q/K).
// MODE 1: A=W, B=X. C[od][gm]; natural store -> dst[bh][d][gm] (V^T natural).
// ---------------------------------------------------------------------------
template <int MODE>
__global__ __launch_bounds__(256) void proj_nat(
    const unsigned short* __restrict__ Xb,   // [4096][1024]
    const unsigned short* __restrict__ Wb,   // [1024][1024]
    const float* __restrict__ bias,
    const int* __restrict__ inv,             // [32][2048] (MODE 0)
    unsigned short* __restrict__ dst)
{
    __shared__ unsigned short At[2][128 * 64];
    __shared__ unsigned short Bt[2][64 * 64];

    const int tid = threadIdx.x;
    const int lane = tid & 63;
    const int wv = tid >> 6;
    const int fr = lane & 15;
    const int fg = lane >> 4;
    const int srw = lane >> 3;
    const int su = lane & 7;

    const int flat = blockIdx.x;            // 0..511
    const int xg = flat & 7;                // XCD group (round-robin dispatch)
    const int j = flat >> 3;                // 0..63

    const unsigned short* Ap; const unsigned short* Bp;
    int m0, n0;
    if constexpr (MODE == 0) {
        // A = X: mtile = xg*4 + (j>>4) in 0..31 ; B = W: ntile = j&15 in 0..15
        Ap = Xb; Bp = Wb;
        m0 = ((xg << 2) + (j >> 4)) * 128;
        n0 = (j & 15) * 64;
    } else {
        // A = W: mtile = j&7 in 0..7 ; B = X: ntile = xg*8 + (j>>3) in 0..63
        Ap = Wb; Bp = Xb;
        m0 = (j & 7) * 128;
        n0 = ((xg << 3) + (j >> 3)) * 64;
    }

    // hoisted per-lane staging sources
    const unsigned short* aS[4]; const unsigned short* bS[2];
#pragma unroll
    for (int i = 0; i < 4; i++) {
        int r = wv * 32 + i * 8 + srw;
        aS[i] = Ap + (size_t)(m0 + r) * DMODEL + ((su ^ (r & 7)) << 3);
    }
#pragma unroll
    for (int i = 0; i < 2; i++) {
        int r = wv * 16 + i * 8 + srw;
        bS[i] = Bp + (size_t)(n0 + r) * DMODEL + ((su ^ (r & 7)) << 3);
    }

    f32x4 acc[2][4];
    const f32x4 fzero = {0.f, 0.f, 0.f, 0.f};
#pragma unroll
    for (int mf = 0; mf < 2; mf++)
#pragma unroll
        for (int nf = 0; nf < 4; nf++) acc[mf][nf] = fzero;

#define PSTAGE(K0, BI)                                                        \
    {                                                                         \
        _Pragma("unroll")                                                     \
        for (int i = 0; i < 4; i++)                                           \
            __builtin_amdgcn_global_load_lds(                                 \
                (const void*)(aS[i] + (K0)),                                  \
                (void*)&At[BI][(wv * 32 + i * 8) * 64], 16, 0, 0);            \
        _Pragma("unroll")                                                     \
        for (int i = 0; i < 2; i++)                                           \
            __builtin_amdgcn_global_load_lds(                                 \
                (const void*)(bS[i] + (K0)),                                  \
                (void*)&Bt[BI][(wv * 16 + i * 8) * 64], 16, 0, 0);            \
    }

    PSTAGE(0, 0);
    __syncthreads();
    int cur = 0;

    for (int kk = 0; kk < 16; kk++) {
        if (kk < 15) PSTAGE((kk + 1) * 64, cur ^ 1);

        short8_t a[2][2], b[4][2];
#pragma unroll
        for (int mf = 0; mf < 2; mf++)
#pragma unroll
            for (int ks = 0; ks < 2; ks++) {
                int r = wv * 32 + mf * 16 + fr;
                int u = (ks * 4 + fg) ^ (fr & 7);
                a[mf][ks] = *(const short8_t*)&At[cur][r * 64 + u * 8];
            }
#pragma unroll
        for (int nf = 0; nf < 4; nf++)
#pragma unroll
            for (int ks = 0; ks < 2; ks++) {
                int r = nf * 16 + fr;
                int u = (ks * 4 + fg) ^ (fr & 7);
                b[nf][ks] = *(const short8_t*)&Bt[cur][r * 64 + u * 8];
            }
#pragma unroll
        for (int ks = 0; ks < 2; ks++)
#pragma unroll
            for (int mf = 0; mf < 2; mf++)
#pragma unroll
                for (int nf = 0; nf < 4; nf++)
                    acc[mf][nf] = MFMA(a[mf][ks], b[nf][ks], acc[mf][nf]);
        __syncthreads();
        cur ^= 1;
    }
#undef PSTAGE

    if constexpr (MODE == 0) {
        // rows gm (scattered via inv), cols dd within ONE head (n0 spans 64)
        const int hh = n0 >> 6;
#pragma unroll
        for (int mf = 0; mf < 2; mf++)
#pragma unroll
            for (int r = 0; r < 4; r++) {
                int gm = m0 + wv * 32 + mf * 16 + fg * 4 + r;   // b*2048+l
                int bb = gm >> 11;
                int bh = bb * NHEAD + hh;
                int pos = inv[(size_t)bh * SEQ + (gm & (SEQ - 1))];
                unsigned short* drow = dst + ((size_t)bh * SEQ + pos) * DK;
#pragma unroll
                for (int nf = 0; nf < 4; nf++) {
                    int dd = (n0 & 63) + nf * 16 + fr;          // = nf*16+fr
                    float v = acc[mf][nf][r] + bias[n0 + nf * 16 + fr];
                    drow[dd] = f2bf(v);
                }
            }
    } else {
        // rows od (head dims), cols gm natural (n0 spans 64 within one b)
        const int bb = n0 >> 11;
#pragma unroll
        for (int mf = 0; mf < 2; mf++)
#pragma unroll
            for (int r = 0; r < 4; r++) {
                int od = m0 + wv * 32 + mf * 16 + fg * 4 + r;   // h*64+d
                int h = od >> 6;
                int bh = bb * NHEAD + h;
                float bv = bias[od];
                unsigned short* drow =
                    dst + ((size_t)bh * DK + (od & 63)) * SEQ + (n0 & (SEQ - 1));
#pragma unroll
                for (int nf = 0; nf < 4; nf++) {
                    float v = acc[mf][nf][r] + bv;
                    drow[nf * 16 + fr] = f2bf(v);
                }
            }
    }
}

// ---------------------------------------------------------------------------
// vperm: Vs[bh][d][pos] = Vn[bh][d][korder[bh][pos]]  (gather along keys)
// ---------------------------------------------------------------------------
__global__ __launch_bounds__(256) void vperm_kernel(
    const unsigned short* __restrict__ Vn, const int* __restrict__ korder,
    unsigned short* __restrict__ Vs)
{
    const int blk = blockIdx.x;       // 0..2047 = bh*64 + d
    const int bh = blk >> 6;
    const int d  = blk & 63;
    const int t = threadIdx.x;        // pos = t*8
    const int* kop = korder + (size_t)bh * SEQ + t * 8;
    const unsigned short* src = Vn + ((size_t)bh * DK + d) * SEQ;
    union { short8_t v; unsigned short u[8]; } o;
#pragma unroll
    for (int j = 0; j < 8; j++) o.u[j] = src[kop[j]];
    *(short8_t*)(Vs + ((size_t)bh * DK + d) * SEQ + t * 8) = o.v;
}

// ---------------------------------------------------------------------------
// LSH flash attention: bucket-sorted, bucket-aligned q-slots, swapped QK^T,
// in-register PV (16x16x16), V-frags hoisted before softmax, psum via MFMA.
// ---------------------------------------------------------------------------
__global__ __launch_bounds__(256) void lsh_attn_kernel(
    const unsigned short* __restrict__ Qs,
    const unsigned short* __restrict__ Ks, const unsigned short* __restrict__ Vst,
    const int* __restrict__ qorder, const int* __restrict__ cnts,
    float* __restrict__ out)
{
    __shared__ unsigned short KtL[2][64 * 64];
    __shared__ unsigned short VtL[2][64 * 64];

    const int tid = threadIdx.x;
    const int lane = tid & 63;
    const int wv = tid >> 6;
    const int fr = lane & 15;
    const int fg = lane >> 4;

    // XCD-grouped mapping: 1056 = 8 XCD x (4 heads x 33 slots)
    const int flat = blockIdx.x;
    const int xcd = flat & 7;
    const int s2 = flat >> 3;                 // 0..131
    const int bh = (xcd << 2) + (s2 / 33);    // b*16 + h
    const int slot = s2 % 33;

    const int nq0 = cnts[bh];
    const int nk0 = cnts[32 + bh];
    const int c0 = (nq0 + 63) >> 6;           // q-tiles covering bucket 0

    int B, qlo, qhi;
    if (slot < c0) {
        B = 0; qlo = slot << 6; qhi = min(qlo + 64, nq0);
    } else {
        B = 1; qlo = nq0 + ((slot - c0) << 6);
        if (qlo >= SEQ) return;               // uniform: safe before barriers
        qhi = min(qlo + 64, SEQ);
    }
    const int klo = B ? (nk0 >> 6) : 0;
    const int khi = B ? (SEQ >> 6) : ((nk0 + 63) >> 6);
    const int nt = khi - klo;

    const size_t base = (size_t)bh * SEQ * DK;
    const unsigned short* Kb = Ks + base;                    // [pos][d]
    const unsigned short* Vb = Vst + (size_t)bh * DK * SEQ;  // [d][pos]

    const int srw = lane >> 3;
    const int su = lane & 7;

    // Q fragments (B-operand of swapped QK: lane fr = q-row qlo + wv*16 + fr)
    short8_t q_hi[2];
    {
        const size_t ro = base + (size_t)(qlo + wv * 16 + fr) * DK;
        q_hi[0] = *(const short8_t*)(Qs + ro + fg * 8);
        q_hi[1] = *(const short8_t*)(Qs + ro + 32 + fg * 8);
    }

    const int swz = fr & 7;
    const int u0 = ((fg ^ swz) << 3);
    const int u1 = (((4 + fg) ^ swz) << 3);
    int vuoff[4];
#pragma unroll
    for (int kg = 0; kg < 4; kg++)
        vuoff[kg] = (((kg * 2 + (fg >> 1)) ^ swz) << 3) + ((fg & 1) << 2);

    const float C2 = 0.18033688011112042f;    // 0.125 * log2(e)
    const float B2 = -14.426950408889634f;    // -10 * log2(e)

    const short4_t ones = {(short)0x3F80, (short)0x3F80, (short)0x3F80, (short)0x3F80};
    f32x4 acc_sum;
    f32x4 o_acc[4];
    const f32x4 fzero = {0.f, 0.f, 0.f, 0.f};
    acc_sum = fzero;
#pragma unroll
    for (int t = 0; t < 4; t++) o_acc[t] = fzero;

#define STAGE(T, BI)                                                          \
    {                                                                         \
        const int k0s = (T) << 6;                                             \
        _Pragma("unroll")                                                     \
        for (int i = 0; i < 2; i++) {                                         \
            const int r = wv * 16 + i * 8 + srw;                              \
            const int uo = ((su ^ (r & 7)) << 3);                             \
            __builtin_amdgcn_global_load_lds(                                 \
                (const void*)(Kb + (size_t)(k0s + r) * DK + uo),              \
                (void*)&KtL[BI][(wv * 16 + i * 8) * 64], 16, 0, 0);           \
            __builtin_amdgcn_global_load_lds(                                 \
                (const void*)(Vb + (size_t)r * SEQ + k0s + uo),               \
                (void*)&VtL[BI][(wv * 16 + i * 8) * 64], 16, 0, 0);           \
        }                                                                     \
    }

    STAGE(klo, 0);
    __syncthreads();
    int cur = 0;

    for (int i = 0; i < nt; i++) {
        if (i + 1 < nt) STAGE(klo + i + 1, cur ^ 1);   // prefetch next tile

        const int k0 = (klo + i) << 6;

        // ---- V fragments into regs early (independent of S) ----
        short4_t vfr[4][4];
#pragma unroll
        for (int dt = 0; dt < 4; dt++)
#pragma unroll
            for (int kg = 0; kg < 4; kg++)
                vfr[dt][kg] = *(const short4_t*)&VtL[cur][(dt * 16 + fr) * 64 + vuoff[kg]];

        // ---- S^T = K Q^T (8 MFMA; A = K rows, B = Q) ----
        f32x4 s[4];
#pragma unroll
        for (int kg = 0; kg < 4; kg++) {
            const int rr = (kg * 16 + fr) * 64;
            short8_t kc0 = *(const short8_t*)&KtL[cur][rr + u0];
            short8_t kc1 = *(const short8_t*)&KtL[cur][rr + u1];
            f32x4 a = fzero;
            a = MFMA(kc0, q_hi[0], a);
            a = MFMA(kc1, q_hi[1], a);
            s[kg] = a;
        }

        // ---- softmax: p = exp2(s*C2 + B2); boundary tile masks by position ----
        short4_t pk[4];
        const bool mixed = B ? (k0 < nk0) : (k0 + 64 > nk0);
        if (!mixed) {
#pragma unroll
            for (int kg = 0; kg < 4; kg++) {
                union { short4_t v; unsigned short u[4]; } P;
#pragma unroll
                for (int r = 0; r < 4; r++)
                    P.u[r] = f2bf(exp2f(fmaf(s[kg][r], C2, B2)));
                pk[kg] = P.v;
            }
        } else {
#pragma unroll
            for (int kg = 0; kg < 4; kg++) {
                union { short4_t v; unsigned short u[4]; } P;
#pragma unroll
                for (int r = 0; r < 4; r++) {
                    int cb = (k0 + kg * 16 + fg * 4 + r) >= nk0;
                    float basev = (cb == B) ? B2 : -1e9f;
                    P.u[r] = f2bf(exp2f(fmaf(s[kg][r], C2, basev)));
                }
                pk[kg] = P.v;
            }
        }

        // ---- psum via MFMA: acc_sum[.][q] += sum_k P^T[k][q] ----
#pragma unroll
        for (int kg = 0; kg < 4; kg++)
            acc_sum = MFMA16(ones, pk[kg], acc_sum);

        // ---- O^T += V^T P^T (in-register A and B) ----
#pragma unroll
        for (int dt = 0; dt < 4; dt++) {
            f32x4 acc = o_acc[dt];
#pragma unroll
            for (int kg = 0; kg < 4; kg++)
                acc = MFMA16(vfr[dt][kg], pk[kg], acc);
            o_acc[dt] = acc;
        }

        __syncthreads();   // drains prefetch + protects buffer reuse
        cur ^= 1;
    }
#undef STAGE

    // acc_sum rows are identical; element 0 already holds the full psum for q=fr
    const float psum = acc_sum[0];

    // ---- epilogue: row q=fr scatter via qorder; cols contiguous -> float4 ----
    const int b = bh >> 4, h = bh & 15;
    const int qpos = qlo + wv * 16 + fr;
    if (qpos < qhi) {
        const int origq = qorder[(size_t)bh * SEQ + qpos];
        const float inv = 1.0f / psum;
        float* orow = out + ((size_t)(b * SEQ + origq)) * DMODEL + h * DK + fg * 4;
#pragma unroll
        for (int dt = 0; dt < 4; dt++) {
            f32x4 v = o_acc[dt];
            v *= inv;
            *(f32x4*)(orow + dt * 16) = v;
        }
    }
}

// ---------------------------------------------------------------------------

extern "C" void kernel_launch(void* const* d_in, const int* in_sizes, int n_in,
                              void* d_out, int out_size, void* d_ws, size_t ws_size,
                              hipStream_t stream)
{
    const float* query = (const float*)d_in[0];
    const float* key   = (const float*)d_in[1];
    const float* value = (const float*)d_in[2];
    const int* hash_q  = (const int*)d_in[3];
    const int* hash_k  = (const int*)d_in[4];
    const float* Wq    = (const float*)d_in[5];
    const float* bq    = (const float*)d_in[6];
    const float* Wk    = (const float*)d_in[7];
    const float* bk    = (const float*)d_in[8];
    const float* Wv    = (const float*)d_in[9];
    const float* bv    = (const float*)d_in[10];
    float* out = (float*)d_out;

    const size_t plane = (size_t)BATCH * NHEAD * SEQ * DK;   // 4,194,304 elems
    unsigned short* ws = (unsigned short*)d_ws;
    unsigned short* pQ    = ws;
    unsigned short* pK    = ws + plane;
    unsigned short* pVt   = ws + 2 * plane;                   // sorted V^T
    unsigned short* pVn   = ws + 3 * plane;                   // natural V^T
    unsigned short* Xslot = ws + 4 * plane;                   // 4M els
    unsigned short* Wslot = ws + 5 * plane;                   // 1M els
    int* ip = (int*)(ws + 5 * plane + (size_t)DMODEL * DMODEL);
    int* qorder = ip;                 // 32*2048
    int* korder = ip + 65536;
    int* qinv   = ip + 131072;
    int* kinv   = ip + 196608;
    int* cnts   = ip + 262144;        // 64

    bucket_kernel<<<64, 256, 0, stream>>>(hash_q, hash_k, qorder, korder,
                                          qinv, kinv, cnts);

    const int cvtBlocks = (int)((plane + (size_t)DMODEL * DMODEL) / 8 / 256);

    cvt_xw_kernel<<<cvtBlocks, 256, 0, stream>>>(query, Wq, Xslot, Wslot);
    proj_nat<0><<<512, 256, 0, stream>>>(Xslot, Wslot, bq, qinv, pQ);

    cvt_xw_kernel<<<cvtBlocks, 256, 0, stream>>>(key, Wk, Xslot, Wslot);
    proj_nat<0><<<512, 256, 0, stream>>>(Xslot, Wslot, bk, kinv, pK);

    cvt_xw_kernel<<<cvtBlocks, 256, 0, stream>>>(value, Wv, Xslot, Wslot);
    proj_nat<1><<<512, 256, 0, stream>>>(Xslot, Wslot, bv, kinv, pVn);

    vperm_kernel<<<2048, 256, 0, stream>>>(pVn, korder, pVt);

    lsh_attn_kernel<<<dim3(1056), 256, 0, stream>>>(pQ, pK, pVt,
                                                    qorder, cnts, out);
}

// Round 11
// 133.257 us; speedup vs baseline: 1.1371x; 1.0232x over previous
//
#include <hip/hip_runtime.h>
#include <hip/hip_bf16.h>
#include <stdint.h>
#include <math.h>

#define NHEAD 16
#define DK 64
#define SEQ 2048
#define BATCH 2
#define DMODEL 1024

typedef __attribute__((ext_vector_type(8))) short short8_t;
typedef __attribute__((ext_vector_type(4))) short short4_t;
typedef __attribute__((ext_vector_type(4))) float f32x4;

#define MFMA(a, b, c) __builtin_amdgcn_mfma_f32_16x16x32_bf16(a, b, c, 0, 0, 0)
#define MFMA16(a, b, c) __builtin_amdgcn_mfma_f32_16x16x16bf16_1k(a, b, c, 0, 0, 0)

__device__ __forceinline__ unsigned short f2bf(float f) {
    union { __hip_bfloat16 b; unsigned short u; } c;
    c.b = __float2bfloat16(f);
    return c.u;
}

// ---------------------------------------------------------------------------
// bucket_kernel: per (bh, which) stable-partition indices by hash value.
// order[pos] = original idx; inv[idx] = pos; cnts[which*32+bh] = #zeros.
// ---------------------------------------------------------------------------
__global__ __launch_bounds__(256) void bucket_kernel(
    const int* __restrict__ hq, const int* __restrict__ hk,
    int* __restrict__ qorder, int* __restrict__ korder,
    int* __restrict__ qinv, int* __restrict__ kinv, int* __restrict__ cnts)
{
    const int blk = blockIdx.x;          // 0..63
    const int bh = blk >> 1;
    const int which = blk & 1;
    const int* src = (which ? hk : hq) + (size_t)bh * SEQ;
    int* dst = (which ? korder : qorder) + (size_t)bh * SEQ;
    int* ivd = (which ? kinv : qinv) + (size_t)bh * SEQ;

    __shared__ int cnt[257];
    const int t = threadIdx.x;           // 0..255
    int h[8]; int c = 0;
#pragma unroll
    for (int j = 0; j < 8; j++) { h[j] = src[t * 8 + j]; c += (h[j] == 0); }
    cnt[t] = c;
    __syncthreads();
    if (t == 0) {
        int run = 0;
        for (int i = 0; i < 256; i++) { int v = cnt[i]; cnt[i] = run; run += v; }
        cnt[256] = run;
    }
    __syncthreads();
    const int nz = cnt[256];
    int zpos = cnt[t];
    int opos = nz + t * 8 - cnt[t];
#pragma unroll
    for (int j = 0; j < 8; j++) {
        int idx = t * 8 + j;
        if (h[j] == 0) { dst[zpos] = idx; ivd[idx] = zpos; zpos++; }
        else           { dst[opos] = idx; ivd[idx] = opos; opos++; }
    }
    if (t == 0) cnts[which * 32 + bh] = nz;
}

// ---------------------------------------------------------------------------
// cvt_xw: X (4M f32) -> bf16, W (1M f32) -> bf16.
// ---------------------------------------------------------------------------
__global__ __launch_bounds__(256) void cvt_xw_kernel(
    const float* __restrict__ X, const float* __restrict__ W,
    unsigned short* __restrict__ Xb, unsigned short* __restrict__ Wb)
{
    const size_t t = (size_t)blockIdx.x * 256 + threadIdx.x;
    const float* src;
    unsigned short* dst;
    size_t i8;
    if (t < 524288) { src = X; dst = Xb; i8 = t * 8; }
    else            { src = W; dst = Wb; i8 = (t - 524288) * 8; }
    f32x4 v0 = *(const f32x4*)(src + i8);
    f32x4 v1 = *(const f32x4*)(src + i8 + 4);
    union { short8_t v; unsigned short u[8]; } o;
#pragma unroll
    for (int j = 0; j < 4; j++) {
        o.u[j]     = f2bf(v0[j]);
        o.u[4 + j] = f2bf(v1[j]);
    }
    *(short8_t*)(dst + i8) = o.v;
}

// ---------------------------------------------------------------------------
// proj_nat: natural-order GEMM, tile 128(A-rows) x 64(B-rows), BK=64,
// double-buffered global_load_lds with COUNTED vmcnt (prefetch stays in
// flight across barriers). Grid 512, XCD-grouped on flat&7.
// MODE 0: A=X, B=W. C[gm][od]; scatter rows via inv -> dst[bh][pos][d] (Q/K).
// MODE 1: A=W, B=X. C[od][gm]; natural store -> dst[bh][d][gm] (V^T natural).
// ---------------------------------------------------------------------------
template <int MODE>
__global__ __launch_bounds__(256) void proj_nat(
    const unsigned short* __restrict__ Xb,   // [4096][1024]
    const unsigned short* __restrict__ Wb,   // [1024][1024]
    const float* __restrict__ bias,
    const int* __restrict__ inv,             // [32][2048] (MODE 0)
    unsigned short* __restrict__ dst)
{
    __shared__ unsigned short At[2][128 * 64];
    __shared__ unsigned short Bt[2][64 * 64];

    const int tid = threadIdx.x;
    const int lane = tid & 63;
    const int wv = tid >> 6;
    const int fr = lane & 15;
    const int fg = lane >> 4;
    const int srw = lane >> 3;
    const int su = lane & 7;

    const int flat = blockIdx.x;            // 0..511
    const int xg = flat & 7;                // XCD group (round-robin dispatch)
    const int j = flat >> 3;                // 0..63

    const unsigned short* Ap; const unsigned short* Bp;
    int m0, n0;
    if constexpr (MODE == 0) {
        Ap = Xb; Bp = Wb;
        m0 = ((xg << 2) + (j >> 4)) * 128;
        n0 = (j & 15) * 64;
    } else {
        Ap = Wb; Bp = Xb;
        m0 = (j & 7) * 128;
        n0 = ((xg << 3) + (j >> 3)) * 64;
    }

    const unsigned short* aS[4]; const unsigned short* bS[2];
#pragma unroll
    for (int i = 0; i < 4; i++) {
        int r = wv * 32 + i * 8 + srw;
        aS[i] = Ap + (size_t)(m0 + r) * DMODEL + ((su ^ (r & 7)) << 3);
    }
#pragma unroll
    for (int i = 0; i < 2; i++) {
        int r = wv * 16 + i * 8 + srw;
        bS[i] = Bp + (size_t)(n0 + r) * DMODEL + ((su ^ (r & 7)) << 3);
    }

    f32x4 acc[2][4];
    const f32x4 fzero = {0.f, 0.f, 0.f, 0.f};
#pragma unroll
    for (int mf = 0; mf < 2; mf++)
#pragma unroll
        for (int nf = 0; nf < 4; nf++) acc[mf][nf] = fzero;

#define PSTAGE(K0, BI)                                                        \
    {                                                                         \
        _Pragma("unroll")                                                     \
        for (int i = 0; i < 4; i++)                                           \
            __builtin_amdgcn_global_load_lds(                                 \
                (const void*)(aS[i] + (K0)),                                  \
                (void*)&At[BI][(wv * 32 + i * 8) * 64], 16, 0, 0);            \
        _Pragma("unroll")                                                     \
        for (int i = 0; i < 2; i++)                                           \
            __builtin_amdgcn_global_load_lds(                                 \
                (const void*)(bS[i] + (K0)),                                  \
                (void*)&Bt[BI][(wv * 16 + i * 8) * 64], 16, 0, 0);            \
    }

    PSTAGE(0, 0);
    int cur = 0;

    for (int kk = 0; kk < 16; kk++) {
        if (kk < 15) {
            PSTAGE((kk + 1) * 64, cur ^ 1);
            asm volatile("s_waitcnt vmcnt(6)" ::: "memory");  // tile kk landed
        } else {
            asm volatile("s_waitcnt vmcnt(0)" ::: "memory");
        }
        __builtin_amdgcn_sched_barrier(0);
        __builtin_amdgcn_s_barrier();
        __builtin_amdgcn_sched_barrier(0);

        short8_t a[2][2], b[4][2];
#pragma unroll
        for (int mf = 0; mf < 2; mf++)
#pragma unroll
            for (int ks = 0; ks < 2; ks++) {
                int r = wv * 32 + mf * 16 + fr;
                int u = (ks * 4 + fg) ^ (fr & 7);
                a[mf][ks] = *(const short8_t*)&At[cur][r * 64 + u * 8];
            }
#pragma unroll
        for (int nf = 0; nf < 4; nf++)
#pragma unroll
            for (int ks = 0; ks < 2; ks++) {
                int r = nf * 16 + fr;
                int u = (ks * 4 + fg) ^ (fr & 7);
                b[nf][ks] = *(const short8_t*)&Bt[cur][r * 64 + u * 8];
            }
#pragma unroll
        for (int ks = 0; ks < 2; ks++)
#pragma unroll
            for (int mf = 0; mf < 2; mf++)
#pragma unroll
                for (int nf = 0; nf < 4; nf++)
                    acc[mf][nf] = MFMA(a[mf][ks], b[nf][ks], acc[mf][nf]);

        __builtin_amdgcn_sched_barrier(0);
        __builtin_amdgcn_s_barrier();      // all reads of buf[cur] done
        __builtin_amdgcn_sched_barrier(0);
        cur ^= 1;
    }
#undef PSTAGE

    if constexpr (MODE == 0) {
        const int hh = n0 >> 6;
#pragma unroll
        for (int mf = 0; mf < 2; mf++)
#pragma unroll
            for (int r = 0; r < 4; r++) {
                int gm = m0 + wv * 32 + mf * 16 + fg * 4 + r;   // b*2048+l
                int bb = gm >> 11;
                int bh = bb * NHEAD + hh;
                int pos = inv[(size_t)bh * SEQ + (gm & (SEQ - 1))];
                unsigned short* drow = dst + ((size_t)bh * SEQ + pos) * DK;
#pragma unroll
                for (int nf = 0; nf < 4; nf++) {
                    float v = acc[mf][nf][r] + bias[n0 + nf * 16 + fr];
                    drow[nf * 16 + fr] = f2bf(v);
                }
            }
    } else {
        const int bb = n0 >> 11;
#pragma unroll
        for (int mf = 0; mf < 2; mf++)
#pragma unroll
            for (int r = 0; r < 4; r++) {
                int od = m0 + wv * 32 + mf * 16 + fg * 4 + r;   // h*64+d
                int h = od >> 6;
                int bh = bb * NHEAD + h;
                float bv = bias[od];
                unsigned short* drow =
                    dst + ((size_t)bh * DK + (od & 63)) * SEQ + (n0 & (SEQ - 1));
#pragma unroll
                for (int nf = 0; nf < 4; nf++) {
                    float v = acc[mf][nf][r] + bv;
                    drow[nf * 16 + fr] = f2bf(v);
                }
            }
    }
}

// ---------------------------------------------------------------------------
// vperm: Vs[bh][d][pos] = Vn[bh][d][korder[bh][pos]]  (gather along keys)
// ---------------------------------------------------------------------------
__global__ __launch_bounds__(256) void vperm_kernel(
    const unsigned short* __restrict__ Vn, const int* __restrict__ korder,
    unsigned short* __restrict__ Vs)
{
    const int blk = blockIdx.x;       // 0..2047 = bh*64 + d
    const int bh = blk >> 6;
    const int d  = blk & 63;
    const int t = threadIdx.x;        // pos = t*8
    const int* kop = korder + (size_t)bh * SEQ + t * 8;
    const unsigned short* src = Vn + ((size_t)bh * DK + d) * SEQ;
    union { short8_t v; unsigned short u[8]; } o;
#pragma unroll
    for (int j = 0; j < 8; j++) o.u[j] = src[kop[j]];
    *(short8_t*)(Vs + ((size_t)bh * DK + d) * SEQ + t * 8) = o.v;
}

// ---------------------------------------------------------------------------
// LSH flash attention: bucket-sorted, bucket-aligned q-slots, swapped QK^T,
// in-register PV (16x16x16), psum via MFMA, and 2-phase staging with COUNTED
// vmcnt: the next tile's global_load_lds stays in flight across barriers.
// ---------------------------------------------------------------------------
__global__ __launch_bounds__(256) void lsh_attn_kernel(
    const unsigned short* __restrict__ Qs,
    const unsigned short* __restrict__ Ks, const unsigned short* __restrict__ Vst,
    const int* __restrict__ qorder, const int* __restrict__ cnts,
    float* __restrict__ out)
{
    __shared__ unsigned short KtL[2][64 * 64];
    __shared__ unsigned short VtL[2][64 * 64];

    const int tid = threadIdx.x;
    const int lane = tid & 63;
    const int wv = tid >> 6;
    const int fr = lane & 15;
    const int fg = lane >> 4;

    // XCD-grouped mapping: 1056 = 8 XCD x (4 heads x 33 slots)
    const int flat = blockIdx.x;
    const int xcd = flat & 7;
    const int s2 = flat >> 3;                 // 0..131
    const int bh = (xcd << 2) + (s2 / 33);    // b*16 + h
    const int slot = s2 % 33;

    const int nq0 = cnts[bh];
    const int nk0 = cnts[32 + bh];
    const int c0 = (nq0 + 63) >> 6;           // q-tiles covering bucket 0

    int B, qlo, qhi;
    if (slot < c0) {
        B = 0; qlo = slot << 6; qhi = min(qlo + 64, nq0);
    } else {
        B = 1; qlo = nq0 + ((slot - c0) << 6);
        if (qlo >= SEQ) return;               // block-uniform: safe w/ barriers
        qhi = min(qlo + 64, SEQ);
    }
    const int klo = B ? (nk0 >> 6) : 0;
    const int khi = B ? (SEQ >> 6) : ((nk0 + 63) >> 6);
    const int nt = khi - klo;

    const size_t base = (size_t)bh * SEQ * DK;
    const unsigned short* Kb = Ks + base;                    // [pos][d]
    const unsigned short* Vb = Vst + (size_t)bh * DK * SEQ;  // [d][pos]

    const int srw = lane >> 3;
    const int su = lane & 7;

    // Q fragments (B-operand of swapped QK: lane fr = q-row qlo + wv*16 + fr)
    short8_t q_hi[2];
    {
        const size_t ro = base + (size_t)(qlo + wv * 16 + fr) * DK;
        q_hi[0] = *(const short8_t*)(Qs + ro + fg * 8);
        q_hi[1] = *(const short8_t*)(Qs + ro + 32 + fg * 8);
    }

    const int swz = fr & 7;
    const int u0 = ((fg ^ swz) << 3);
    const int u1 = (((4 + fg) ^ swz) << 3);
    int vuoff[4];
#pragma unroll
    for (int kg = 0; kg < 4; kg++)
        vuoff[kg] = (((kg * 2 + (fg >> 1)) ^ swz) << 3) + ((fg & 1) << 2);

    const float C2 = 0.18033688011112042f;    // 0.125 * log2(e)
    const float B2 = -14.426950408889634f;    // -10 * log2(e)

    const short4_t ones = {(short)0x3F80, (short)0x3F80, (short)0x3F80, (short)0x3F80};
    f32x4 acc_sum;
    f32x4 o_acc[4];
    const f32x4 fzero = {0.f, 0.f, 0.f, 0.f};
    acc_sum = fzero;
#pragma unroll
    for (int t = 0; t < 4; t++) o_acc[t] = fzero;

#define STAGE(T, BI)                                                          \
    {                                                                         \
        const int k0s = (T) << 6;                                             \
        _Pragma("unroll")                                                     \
        for (int i = 0; i < 2; i++) {                                         \
            const int r = wv * 16 + i * 8 + srw;                              \
            const int uo = ((su ^ (r & 7)) << 3);                             \
            __builtin_amdgcn_global_load_lds(                                 \
                (const void*)(Kb + (size_t)(k0s + r) * DK + uo),              \
                (void*)&KtL[BI][(wv * 16 + i * 8) * 64], 16, 0, 0);           \
            __builtin_amdgcn_global_load_lds(                                 \
                (const void*)(Vb + (size_t)r * SEQ + k0s + uo),               \
                (void*)&VtL[BI][(wv * 16 + i * 8) * 64], 16, 0, 0);           \
        }                                                                     \
    }

    STAGE(klo, 0);
    int cur = 0;

    for (int i = 0; i < nt; i++) {
        if (i + 1 < nt) {
            STAGE(klo + i + 1, cur ^ 1);      // 4 more loads in flight
            asm volatile("s_waitcnt vmcnt(4)" ::: "memory");  // tile i landed
        } else {
            asm volatile("s_waitcnt vmcnt(0)" ::: "memory");
        }
        __builtin_amdgcn_sched_barrier(0);
        __builtin_amdgcn_s_barrier();         // tile i visible to all waves
        __builtin_amdgcn_sched_barrier(0);

        const int k0 = (klo + i) << 6;

        // ---- V fragments into regs early (independent of S) ----
        short4_t vfr[4][4];
#pragma unroll
        for (int dt = 0; dt < 4; dt++)
#pragma unroll
            for (int kg = 0; kg < 4; kg++)
                vfr[dt][kg] = *(const short4_t*)&VtL[cur][(dt * 16 + fr) * 64 + vuoff[kg]];

        // ---- S^T = K Q^T (8 MFMA; A = K rows, B = Q) ----
        f32x4 s[4];
#pragma unroll
        for (int kg = 0; kg < 4; kg++) {
            const int rr = (kg * 16 + fr) * 64;
            short8_t kc0 = *(const short8_t*)&KtL[cur][rr + u0];
            short8_t kc1 = *(const short8_t*)&KtL[cur][rr + u1];
            f32x4 a = fzero;
            a = MFMA(kc0, q_hi[0], a);
            a = MFMA(kc1, q_hi[1], a);
            s[kg] = a;
        }

        // ---- softmax: p = exp2(s*C2 + B2); boundary tile masks by position ----
        short4_t pk[4];
        const bool mixed = B ? (k0 < nk0) : (k0 + 64 > nk0);
        if (!mixed) {
#pragma unroll
            for (int kg = 0; kg < 4; kg++) {
                union { short4_t v; unsigned short u[4]; } P;
#pragma unroll
                for (int r = 0; r < 4; r++)
                    P.u[r] = f2bf(exp2f(fmaf(s[kg][r], C2, B2)));
                pk[kg] = P.v;
            }
        } else {
#pragma unroll
            for (int kg = 0; kg < 4; kg++) {
                union { short4_t v; unsigned short u[4]; } P;
#pragma unroll
                for (int r = 0; r < 4; r++) {
                    int cb = (k0 + kg * 16 + fg * 4 + r) >= nk0;
                    float basev = (cb == B) ? B2 : -1e9f;
                    P.u[r] = f2bf(exp2f(fmaf(s[kg][r], C2, basev)));
                }
                pk[kg] = P.v;
            }
        }

        // ---- psum via MFMA: acc_sum[.][q] += sum_k P^T[k][q] ----
#pragma unroll
        for (int kg = 0; kg < 4; kg++)
            acc_sum = MFMA16(ones, pk[kg], acc_sum);

        // ---- O^T += V^T P^T (in-register A and B) ----
#pragma unroll
        for (int dt = 0; dt < 4; dt++) {
            f32x4 acc = o_acc[dt];
#pragma unroll
            for (int kg = 0; kg < 4; kg++)
                acc = MFMA16(vfr[dt][kg], pk[kg], acc);
            o_acc[dt] = acc;
        }

        __builtin_amdgcn_sched_barrier(0);
        __builtin_amdgcn_s_barrier();         // buf[cur] fully consumed
        __builtin_amdgcn_sched_barrier(0);
        cur ^= 1;
    }
#undef STAGE

    // acc_sum rows are identical; element 0 already holds the full psum for q=fr
    const float psum = acc_sum[0];

    // ---- epilogue: row q=fr scatter via qorder; cols contiguous -> float4 ----
    const int b = bh >> 4, h = bh & 15;
    const int qpos = qlo + wv * 16 + fr;
    if (qpos < qhi) {
        const int origq = qorder[(size_t)bh * SEQ + qpos];
        const float inv = 1.0f / psum;
        float* orow = out + ((size_t)(b * SEQ + origq)) * DMODEL + h * DK + fg * 4;
#pragma unroll
        for (int dt = 0; dt < 4; dt++) {
            f32x4 v = o_acc[dt];
            v *= inv;
            *(f32x4*)(orow + dt * 16) = v;
        }
    }
}

// ---------------------------------------------------------------------------

extern "C" void kernel_launch(void* const* d_in, const int* in_sizes, int n_in,
                              void* d_out, int out_size, void* d_ws, size_t ws_size,
                              hipStream_t stream)
{
    const float* query = (const float*)d_in[0];
    const float* key   = (const float*)d_in[1];
    const float* value = (const float*)d_in[2];
    const int* hash_q  = (const int*)d_in[3];
    const int* hash_k  = (const int*)d_in[4];
    const float* Wq    = (const float*)d_in[5];
    const float* bq    = (const float*)d_in[6];
    const float* Wk    = (const float*)d_in[7];
    const float* bk    = (const float*)d_in[8];
    const float* Wv    = (const float*)d_in[9];
    const float* bv    = (const float*)d_in[10];
    float* out = (float*)d_out;

    const size_t plane = (size_t)BATCH * NHEAD * SEQ * DK;   // 4,194,304 elems
    unsigned short* ws = (unsigned short*)d_ws;
    unsigned short* pQ    = ws;
    unsigned short* pK    = ws + plane;
    unsigned short* pVt   = ws + 2 * plane;                   // sorted V^T
    unsigned short* pVn   = ws + 3 * plane;                   // natural V^T
    unsigned short* Xslot = ws + 4 * plane;                   // 4M els
    unsigned short* Wslot = ws + 5 * plane;                   // 1M els
    int* ip = (int*)(ws + 5 * plane + (size_t)DMODEL * DMODEL);
    int* qorder = ip;                 // 32*2048
    int* korder = ip + 65536;
    int* qinv   = ip + 131072;
    int* kinv   = ip + 196608;
    int* cnts   = ip + 262144;        // 64

    bucket_kernel<<<64, 256, 0, stream>>>(hash_q, hash_k, qorder, korder,
                                          qinv, kinv, cnts);

    const int cvtBlocks = (int)((plane + (size_t)DMODEL * DMODEL) / 8 / 256);

    cvt_xw_kernel<<<cvtBlocks, 256, 0, stream>>>(query, Wq, Xslot, Wslot);
    proj_nat<0><<<512, 256, 0, stream>>>(Xslot, Wslot, bq, qinv, pQ);

    cvt_xw_kernel<<<cvtBlocks, 256, 0, stream>>>(key, Wk, Xslot, Wslot);
    proj_nat<0><<<512, 256, 0, stream>>>(Xslot, Wslot, bk, kinv, pK);

    cvt_xw_kernel<<<cvtBlocks, 256, 0, stream>>>(value, Wv, Xslot, Wslot);
    proj_nat<1><<<512, 256, 0, stream>>>(Xslot, Wslot, bv, kinv, pVn);

    vperm_kernel<<<2048, 256, 0, stream>>>(pVn, korder, pVt);

    lsh_attn_kernel<<<dim3(1056), 256, 0, stream>>>(pQ, pK, pVt,
                                                    qorder, cnts, out);
}